// Round 13
// baseline (96.905 us; speedup 1.0000x reference)
//
#include <hip/hip_runtime.h>

// LogSparse attention: B=4, L=2048, H=8, D=64, fp32.
// Query i attends to {i} ∪ {i - 2^k}: offsets {0,1,2,4,...,1024} (<=12).
// Block = (b, h, strip of 32 queries); 4 waves; one pass (8 queries/wave).
// Short offsets {0..32} from LDS (K f16 + fdot2, V f32); far offsets
// {64..1024} inline from global (f32), loads ordered early for overlap.
// Occupancy-max variant: no far preload arrays -> launch_bounds(256,6)
// (VGPR<=85) -> 6 blocks/CU (LDS 24KB) = 24 waves/CU.

typedef float  f32x4 __attribute__((ext_vector_type(4)));
typedef __fp16 f16x2 __attribute__((ext_vector_type(2)));
typedef __fp16 f16x8 __attribute__((ext_vector_type(8)));

constexpr int B = 4, L = 2048, H = 8, D = 64;
constexpr int STRIP = 32, WIN = 32, LROWS = STRIP + WIN;  // 64 staged rows
constexpr int NWG = B * H * (L / STRIP);                  // 2048 blocks

__global__ __launch_bounds__(256, 6) void logsparse_attn_kernel(
    const float* __restrict__ Qg, const float* __restrict__ Kg,
    const float* __restrict__ Vg, float* __restrict__ Og) {
  __shared__ __fp16 Ksh[LROWS * D];   // 8 KB
  __shared__ float  Vsh[LROWS * D];   // 16 KB  -> 24 KB/block

  // bid -> (b,h,strip): XCD-chunked; each XCD owns 4 (b,h) pairs (~4MB = L2)
  const int bid   = blockIdx.x;
  const int xcd   = bid & 7;
  const int kk    = bid >> 3;              // 0..255
  const int bh    = xcd * 4 + (kk >> 6);   // 0..31
  const int strip = kk & 63;
  const int b = bh >> 3, h = bh & 7;
  const int s = strip * STRIP;

  const int tid  = threadIdx.x;
  const int wv   = tid >> 6;               // wave 0..3
  const int lane = tid & 63;
  const int g    = lane >> 3;              // query in wave 0..7
  const int dl   = lane & 7;               // elem octet 0..7

  // ---- stage K (f16, inline convert): 512 16B-chunks, 2 per thread ----
  #pragma unroll
  for (int cc = 0; cc < 2; ++cc) {
    const int c = tid + cc * 256;
    const int r = c >> 3, part = c & 7;
    const int j = s - WIN + r;
    const int jc = j < 0 ? 0 : j;          // clamped; masked in compute
    const float* src = Kg + (((uint32_t)(b * L + jc)) * H + h) * D + part * 8;
    const f32x4 a0 = *(const f32x4*)src;
    const f32x4 a1 = *(const f32x4*)(src + 4);
    const f16x2 h0 = __builtin_amdgcn_cvt_pkrtz(a0.x, a0.y);
    const f16x2 h1 = __builtin_amdgcn_cvt_pkrtz(a0.z, a0.w);
    const f16x2 h2 = __builtin_amdgcn_cvt_pkrtz(a1.x, a1.y);
    const f16x2 h3 = __builtin_amdgcn_cvt_pkrtz(a1.z, a1.w);
    const f16x8 hv = {h0.x, h0.y, h1.x, h1.y, h2.x, h2.y, h3.x, h3.y};
    *(f16x8*)&Ksh[r * D + part * 8] = hv;
  }
  // ---- stage V (fp32): 1024 16B-chunks, 4 per thread ----
  #pragma unroll
  for (int cc = 0; cc < 4; ++cc) {
    const int c = tid + cc * 256;
    const int r = c >> 4, part = c & 15;
    const int j = s - WIN + r;
    const int jc = j < 0 ? 0 : j;
    *(f32x4*)&Vsh[r * D + part * 4] =
        *(const f32x4*)(Vg + (((uint32_t)(b * L + jc)) * H + h) * D + part * 4);
  }
  __syncthreads();

  const int il = wv * 8 + g;               // query-in-strip 0..31
  const int i  = s + il;
  const uint32_t qb = (((uint32_t)(b * L + i)) * H + h) * D + dl * 8;

  f32x4 qa = *(const f32x4*)(Qg + qb);
  f32x4 qc = *(const f32x4*)(Qg + qb + 4);
  // fold softmax scale (1/8) and log2(e): base-2 softmax
  const float qs = 0.125f * 1.4426950408889634f;
  qa *= qs;  qc *= qs;

  float sc[12];
  // ---- FAR scores first (global f32; loads issue early, overlap below) ----
  #pragma unroll
  for (int t = 0; t < 5; ++t) {
    const int off = 64 << t;
    const int jc  = (off <= i) ? (i - off) : 0;
    const float* rp = Kg + (((uint32_t)(b * L + jc)) * H + h) * D + dl * 8;
    const f32x4 k0 = *(const f32x4*)rp;
    const f32x4 k1 = *(const f32x4*)(rp + 4);
    float p = qa.x * k0.x + qa.y * k0.y + qa.z * k0.z + qa.w * k0.w
            + qc.x * k1.x + qc.y * k1.y + qc.z * k1.z + qc.w * k1.w;
    p += __shfl_xor(p, 1, 64);
    p += __shfl_xor(p, 2, 64);
    p += __shfl_xor(p, 4, 64);
    sc[7 + t] = (off <= i) ? p : -1e30f;
  }

  // ---- short scores {0,1,2,4,8,16,32} from f16 LDS via fdot2 ----
  const f16x2 q01 = __builtin_amdgcn_cvt_pkrtz(qa.x, qa.y);
  const f16x2 q23 = __builtin_amdgcn_cvt_pkrtz(qa.z, qa.w);
  const f16x2 q45 = __builtin_amdgcn_cvt_pkrtz(qc.x, qc.y);
  const f16x2 q67 = __builtin_amdgcn_cvt_pkrtz(qc.z, qc.w);
  #pragma unroll
  for (int t = 0; t < 7; ++t) {
    const int off = (t == 0) ? 0 : (1 << (t - 1));
    const int r   = il + WIN - off;
    const f16x8 kv = *(const f16x8*)&Ksh[r * D + dl * 8];
    const f16x2 k01 = {kv[0], kv[1]}, k23 = {kv[2], kv[3]};
    const f16x2 k45 = {kv[4], kv[5]}, k67 = {kv[6], kv[7]};
    float p = __builtin_amdgcn_fdot2(q01, k01, 0.f, false);
    p = __builtin_amdgcn_fdot2(q23, k23, p, false);
    p = __builtin_amdgcn_fdot2(q45, k45, p, false);
    p = __builtin_amdgcn_fdot2(q67, k67, p, false);
    p += __shfl_xor(p, 1, 64);
    p += __shfl_xor(p, 2, 64);
    p += __shfl_xor(p, 4, 64);
    sc[t] = (off <= i) ? p : -1e30f;
  }

  // ---- softmax over 12 (base-2). sc[0] (self) always valid. ----
  const float ma = fmaxf(fmaxf(sc[0], sc[1]), fmaxf(sc[2], sc[3]));
  const float mb = fmaxf(fmaxf(sc[4], sc[5]), fmaxf(sc[6], sc[7]));
  const float mc = fmaxf(fmaxf(sc[8], sc[9]), fmaxf(sc[10], sc[11]));
  const float m  = fmaxf(fmaxf(ma, mb), mc);
  #pragma unroll
  for (int t = 0; t < 12; ++t) sc[t] = __builtin_amdgcn_exp2f(sc[t] - m);
  const float sa = (sc[0] + sc[1]) + (sc[2] + sc[3]);
  const float sb = (sc[4] + sc[5]) + (sc[6] + sc[7]);
  const float sd = (sc[8] + sc[9]) + (sc[10] + sc[11]);
  const float inv = __builtin_amdgcn_rcpf(sa + sb + sd);

  // ---- PV: far first (global loads issue early), short from LDS after ----
  f32x4 aa = {0.f, 0.f, 0.f, 0.f};
  f32x4 ab = {0.f, 0.f, 0.f, 0.f};
  #pragma unroll
  for (int t = 0; t < 5; ++t) {
    const int off = 64 << t;
    const int jc  = (off <= i) ? (i - off) : 0;
    const float* vp = Vg + (((uint32_t)(b * L + jc)) * H + h) * D + dl * 8;
    const f32x4 v0 = *(const f32x4*)vp;
    const f32x4 v1 = *(const f32x4*)(vp + 4);
    aa += sc[7 + t] * v0;
    ab += sc[7 + t] * v1;
  }
  #pragma unroll
  for (int t = 0; t < 7; ++t) {
    const int off = (t == 0) ? 0 : (1 << (t - 1));
    const int r   = il + WIN - off;
    const f32x4 v0 = *(const f32x4*)&Vsh[r * D + dl * 8];
    const f32x4 v1 = *(const f32x4*)&Vsh[r * D + dl * 8 + 4];
    aa += sc[t] * v0;
    ab += sc[t] * v1;
  }
  aa *= inv;  ab *= inv;
  __builtin_nontemporal_store(aa, reinterpret_cast<f32x4*>(Og + qb));
  __builtin_nontemporal_store(ab, reinterpret_cast<f32x4*>(Og + qb + 4));
}

extern "C" void kernel_launch(void* const* d_in, const int* in_sizes, int n_in,
                              void* d_out, int out_size, void* d_ws, size_t ws_size,
                              hipStream_t stream) {
  const float* Q = (const float*)d_in[0];
  const float* K = (const float*)d_in[1];
  const float* V = (const float*)d_in[2];
  float* O = (float*)d_out;

  logsparse_attn_kernel<<<NWG, 256, 0, stream>>>(Q, K, V, O);
}